// Round 1
// baseline (171.895 us; speedup 1.0000x reference)
//
#include <hip/hip_runtime.h>
#include <math.h>

// Problem constants
#define M_TOKENS 16384   // B*S = 4*4096
#define E_EXPERTS 64
#define K_DIM 2048
#define KSPLIT 4
#define KCHUNK (K_DIM / KSPLIT)   // 512

// ---------------------------------------------------------------------------
// Kernel 1: partial gates. Lane = token. Each lane accumulates all 64 experts
// over a K-chunk. W row W[k][0..63] is wave-uniform -> scalar loads.
// Partials stored transposed: part[kc][e][token] so stores (and the reduce
// kernel's loads) are lane-coalesced.
// ---------------------------------------------------------------------------
__global__ __launch_bounds__(64) void gates_partial_kernel(
    const float* __restrict__ x, const float* __restrict__ W,
    float* __restrict__ part) {
  const int bid = blockIdx.x;
  const int group = bid >> 2;        // token group (64 tokens)
  const int kc = bid & 3;            // K-chunk id
  const int t = group * 64 + threadIdx.x;

  const float* xrow = x + (size_t)t * K_DIM + (size_t)kc * KCHUNK;
  const float* wbase = W + (size_t)kc * KCHUNK * E_EXPERTS;

  float acc[E_EXPERTS];
#pragma unroll
  for (int e = 0; e < E_EXPERTS; ++e) acc[e] = 0.0f;

  for (int k4 = 0; k4 < KCHUNK; k4 += 4) {
    float4 xv = *reinterpret_cast<const float4*>(xrow + k4);
    float xs[4] = {xv.x, xv.y, xv.z, xv.w};
#pragma unroll
    for (int kk = 0; kk < 4; ++kk) {
      const float* wrow = wbase + (size_t)(k4 + kk) * E_EXPERTS;
#pragma unroll
      for (int e = 0; e < E_EXPERTS; ++e) {
        acc[e] = fmaf(xs[kk], wrow[e], acc[e]);
      }
    }
  }

  float* pbase = part + (size_t)kc * E_EXPERTS * M_TOKENS + t;
#pragma unroll
  for (int e = 0; e < E_EXPERTS; ++e) {
    pbase[(size_t)e * M_TOKENS] = acc[e];
  }
}

// ---------------------------------------------------------------------------
// Kernel 2: reduce partials + bias, top-2, softmax over the 2 logits.
// Thread = token. All loads coalesced (consecutive tokens in consecutive
// lanes, expert/chunk index uniform).
// ---------------------------------------------------------------------------
__global__ __launch_bounds__(256) void reduce_topk_kernel(
    const float* __restrict__ part, const float* __restrict__ bias,
    float* __restrict__ out) {
  const int t = blockIdx.x * 256 + threadIdx.x;

  float m1 = -INFINITY, m2 = -INFINITY;
  int i1 = 0, i2 = 0;

  for (int e = 0; e < E_EXPERTS; ++e) {
    float g = bias[e];
#pragma unroll
    for (int kc = 0; kc < KSPLIT; ++kc) {
      g += part[((size_t)kc * E_EXPERTS + e) * M_TOKENS + t];
    }
    if (g > m1) {
      m2 = m1; i2 = i1;
      m1 = g; i1 = e;
    } else if (g > m2) {
      m2 = g; i2 = e;
    }
  }

  // softmax over [m1, m2] (m1 >= m2)
  float w0 = 1.0f / (1.0f + expf(m2 - m1));
  out[2 * t + 0] = w0;
  out[2 * t + 1] = 1.0f - w0;
  float* oidx = out + 2 * (size_t)M_TOKENS;
  oidx[2 * t + 0] = (float)i1;
  oidx[2 * t + 1] = (float)i2;
}

// ---------------------------------------------------------------------------
// Fallback: fully fused, no workspace (KSPLIT=1 inline). Only used if
// ws_size is too small for the partials buffer.
// ---------------------------------------------------------------------------
__global__ __launch_bounds__(64) void router_fused_kernel(
    const float* __restrict__ x, const float* __restrict__ W,
    const float* __restrict__ bias, float* __restrict__ out) {
  const int t = blockIdx.x * 64 + threadIdx.x;
  const float* xrow = x + (size_t)t * K_DIM;

  float acc[E_EXPERTS];
#pragma unroll
  for (int e = 0; e < E_EXPERTS; ++e) acc[e] = 0.0f;

  for (int k4 = 0; k4 < K_DIM; k4 += 4) {
    float4 xv = *reinterpret_cast<const float4*>(xrow + k4);
    float xs[4] = {xv.x, xv.y, xv.z, xv.w};
#pragma unroll
    for (int kk = 0; kk < 4; ++kk) {
      const float* wrow = W + (size_t)(k4 + kk) * E_EXPERTS;
#pragma unroll
      for (int e = 0; e < E_EXPERTS; ++e) {
        acc[e] = fmaf(xs[kk], wrow[e], acc[e]);
      }
    }
  }

  float m1 = -INFINITY, m2 = -INFINITY;
  int i1 = 0, i2 = 0;
#pragma unroll
  for (int e = 0; e < E_EXPERTS; ++e) {
    float g = acc[e] + bias[e];
    if (g > m1) {
      m2 = m1; i2 = i1;
      m1 = g; i1 = e;
    } else if (g > m2) {
      m2 = g; i2 = e;
    }
  }

  float w0 = 1.0f / (1.0f + expf(m2 - m1));
  out[2 * t + 0] = w0;
  out[2 * t + 1] = 1.0f - w0;
  float* oidx = out + 2 * (size_t)M_TOKENS;
  oidx[2 * t + 0] = (float)i1;
  oidx[2 * t + 1] = (float)i2;
}

extern "C" void kernel_launch(void* const* d_in, const int* in_sizes, int n_in,
                              void* d_out, int out_size, void* d_ws, size_t ws_size,
                              hipStream_t stream) {
  const float* x = (const float*)d_in[0];
  const float* W = (const float*)d_in[1];
  const float* b = (const float*)d_in[2];
  float* out = (float*)d_out;

  const size_t need = (size_t)KSPLIT * E_EXPERTS * M_TOKENS * sizeof(float);
  if (ws_size >= need) {
    float* part = (float*)d_ws;
    gates_partial_kernel<<<(M_TOKENS / 64) * KSPLIT, 64, 0, stream>>>(x, W, part);
    reduce_topk_kernel<<<M_TOKENS / 256, 256, 0, stream>>>(part, b, out);
  } else {
    router_fused_kernel<<<M_TOKENS / 64, 64, 0, stream>>>(x, W, b, out);
  }
}